// Round 5
// baseline (154.756 us; speedup 1.0000x reference)
//
#include <hip/hip_runtime.h>
#include <math.h>

#define INPUT_DIM 256
#define N_CLASSES 100
#define MAX_DEPTH 12
#define N_NODES   4095
#define N_LEAVES  4096

#define TPB   512              // 8 waves, 1 block/CU (LDS ~150 KB)
#define NWAVE (TPB / 64)
#define CHUNK 64               // rows staged per chunk
#define RPW   (CHUNK / NWAVE)  // rows DMA'd per wave = 8
#define LPW   (CHUNK / NWAVE)  // traversal lanes active per wave = 8
#define ROWP  260              // padded row stride in floats (1040 B = 65*16; bank=(4r+f)%32)
#define NF4   (N_CLASSES / 4)  // 25 float4 per output row
#define NBLK  256              // 1 persistent block per CU

#define WAITV(N) asm volatile("s_waitcnt vmcnt(" #N ")" ::: "memory")
#define WAITLGKM() asm volatile("s_waitcnt lgkmcnt(0)" ::: "memory")

typedef float f32x4 __attribute__((ext_vector_type(4)));

__device__ __forceinline__ void async_load16(const void* gsrc, void* ldst) {
    __builtin_amdgcn_global_load_lds(
        (const __attribute__((address_space(1))) unsigned int*)gsrc,
        (__attribute__((address_space(3))) unsigned int*)ldst, 16, 0, 0);
}

// ---------------------------------------------------------------------------
// Kernel 1: row-softmax of leaf_probabilities [4096 x 100] -> tab
// ---------------------------------------------------------------------------
__global__ __launch_bounds__(64) void softmax_rows_kernel(
    const float* __restrict__ lp, float* __restrict__ tab) {
    const int row  = blockIdx.x;
    const int lane = threadIdx.x;
    const float* src = lp + (size_t)row * N_CLASSES;

    float v0 = src[lane];
    float v1 = (lane + 64 < N_CLASSES) ? src[lane + 64] : -INFINITY;

    float m = fmaxf(v0, v1);
    #pragma unroll
    for (int off = 32; off > 0; off >>= 1) m = fmaxf(m, __shfl_xor(m, off));

    float e0 = expf(v0 - m);
    float e1 = (lane + 64 < N_CLASSES) ? expf(v1 - m) : 0.0f;
    float s = e0 + e1;
    #pragma unroll
    for (int off = 32; off > 0; off >>= 1) s += __shfl_xor(s, off);

    const float inv = 1.0f / s;
    tab[(size_t)row * N_CLASSES + lane] = e0 * inv;
    if (lane + 64 < N_CLASSES)
        tab[(size_t)row * N_CLASSES + lane + 64] = e1 * inv;
}

// ---------------------------------------------------------------------------
// Kernel 2: streamed traversal, 1 block/CU, 8 waves, CHUNK=64 double-buffered.
// DMA (global_load_lds_dwordx4, 1/row) prefetches chunk i+1 while chunk i is
// traversed; WAITV(8) keeps the 8 newest (next-chunk) DMAs in flight.
// Traversal: 64 chains spread over 8 waves (8 lanes each); node table in LDS.
// Output: coalesced f32x4 gather from L2-resident softmax table.
// LDS: 2*64*1040 + 16380 + 4096 + 256 = 150.2 KB.
// ---------------------------------------------------------------------------
__global__ __launch_bounds__(TPB) void tree_stream_kernel(
    const float* __restrict__ x,
    const float* __restrict__ split_features,
    const float* __restrict__ split_thresholds,
    const f32x4* __restrict__ tab4,
    f32x4* __restrict__ out4,
    int batch, int nchunks) {
    __shared__ float         s_rows[2][CHUNK][ROWP];
    __shared__ float         s_thr[N_NODES];
    __shared__ unsigned char s_feat[N_NODES + 1];
    __shared__ int           s_leaf[CHUNK];

    if (blockIdx.x >= (unsigned)nchunks) return;   // block-uniform exit

    const int tid  = threadIdx.x;
    const int wid  = tid >> 6;
    const int lane = tid & 63;

    // ---- node table -> LDS ----
    for (int i = tid; i < N_NODES; i += TPB) {
        s_thr[i] = split_thresholds[i];
        int f = (int)floorf(split_features[i]);
        s_feat[i] = (unsigned char)min(max(f, 0), INPUT_DIM - 1);
    }

    // ---- stage: wave `wid` DMAs rows wid*8 .. wid*8+7 of chunk c ----
    auto stage = [&](int c, int buf) {
        const int cbase = c * CHUNK;
        #pragma unroll
        for (int j = 0; j < RPW; ++j) {
            const int r = wid * RPW + j;            // wave-uniform LDS dest base
            int s = cbase + r;
            if (s >= batch) s = batch - 1;          // clamp: loads valid data
            const float* src = x + (size_t)s * INPUT_DIM + lane * 4;
            async_load16((const void*)src, (void*)&s_rows[buf][r][0]);
        }
    };

    const int stride = gridDim.x;
    int c = blockIdx.x;

    stage(c, 0);
    __syncthreads();          // drains node-table writes AND chunk0 DMA

    int i = 0;
    for (; c < nchunks; c += stride, ++i) {
        const int cur = i & 1;

        // issue next chunk's DMA, then wait only for the CURRENT chunk
        // (the 8 newest ops are the new DMAs; everything older — current
        //  chunk's DMAs and last chunk's output stores — must retire)
        const int cnext = c + stride;
        if (cnext < nchunks) {
            stage(cnext, cur ^ 1);
            WAITV(8);
        } else {
            WAITV(0);
        }
        __builtin_amdgcn_sched_barrier(0);
        __builtin_amdgcn_s_barrier();
        __builtin_amdgcn_sched_barrier(0);

        // ---- traversal: 8 lanes per wave, sample = wid*8 + lane ----
        if (lane < LPW) {
            const int r = wid * LPW + lane;
            const float* row = &s_rows[cur][r][0];
            int n = 0;
            #pragma unroll
            for (int d = 0; d < MAX_DEPTH; ++d) {
                const int   f = s_feat[n];
                const float t = s_thr[n];
                n = 2 * n + 1 + (row[f] > t ? 1 : 0);
            }
            s_leaf[r] = n - N_NODES;
        }
        WAITLGKM();           // commit s_leaf writes before barrier
        __builtin_amdgcn_sched_barrier(0);
        __builtin_amdgcn_s_barrier();
        __builtin_amdgcn_sched_barrier(0);

        // ---- coalesced output: out[b,:] = tab[leaf[b],:] ----
        const int cbase = c * CHUNK;
        const int nsamp = min(CHUNK, batch - cbase);
        const int maxj  = nsamp * NF4;
        const size_t g4 = (size_t)cbase * NF4;
        for (int j = tid; j < maxj; j += TPB) {
            const int s = j / NF4;                  // magic-div by 25
            const int q = j - s * NF4;
            f32x4 v = tab4[(size_t)s_leaf[s] * NF4 + q];
            __builtin_nontemporal_store(v, &out4[g4 + j]);
        }
        // next iteration's top barrier orders s_leaf / row-buffer reuse
    }
}

// ---------------------------------------------------------------------------
// Fallback (ws too small): fully fused, per-thread softmax.
// ---------------------------------------------------------------------------
__global__ __launch_bounds__(256) void fused_kernel(
    const float* __restrict__ x,
    const float* __restrict__ split_features,
    const float* __restrict__ split_thresholds,
    const float* __restrict__ lp,
    float* __restrict__ out, int batch) {
    __shared__ float2 s_nodes[N_NODES];
    for (int i = threadIdx.x; i < N_NODES; i += blockDim.x) {
        int f = (int)floorf(split_features[i]);
        f = min(max(f, 0), INPUT_DIM - 1);
        float2 n; n.x = split_thresholds[i]; n.y = __int_as_float(f);
        s_nodes[i] = n;
    }
    __syncthreads();

    const int b = blockIdx.x * blockDim.x + threadIdx.x;
    if (b >= batch) return;

    const float* row = x + (size_t)b * INPUT_DIM;
    int node = 0;
    #pragma unroll
    for (int d = 0; d < MAX_DEPTH; ++d) {
        const float2 n = s_nodes[node];
        const float val = row[__float_as_int(n.y)];
        node = 2 * node + 1 + (val > n.x ? 1 : 0);
    }
    const int leaf = node - N_NODES;

    const float* src = lp + (size_t)leaf * N_CLASSES;
    float m = -INFINITY;
    for (int cidx = 0; cidx < N_CLASSES; ++cidx) m = fmaxf(m, src[cidx]);
    float s = 0.0f;
    float e[N_CLASSES];
    for (int cidx = 0; cidx < N_CLASSES; ++cidx) { e[cidx] = expf(src[cidx] - m); s += e[cidx]; }
    const float inv = 1.0f / s;
    float* dst = out + (size_t)b * N_CLASSES;
    for (int cidx = 0; cidx < N_CLASSES; ++cidx) dst[cidx] = e[cidx] * inv;
}

// ---------------------------------------------------------------------------
extern "C" void kernel_launch(void* const* d_in, const int* in_sizes, int n_in,
                              void* d_out, int out_size, void* d_ws, size_t ws_size,
                              hipStream_t stream) {
    const float* x  = (const float*)d_in[0];
    const float* sf = (const float*)d_in[1];
    const float* st = (const float*)d_in[2];
    const float* lp = (const float*)d_in[3];
    float* out = (float*)d_out;

    const int batch = in_sizes[0] / INPUT_DIM;

    const size_t tab_bytes = (size_t)N_LEAVES * N_CLASSES * sizeof(float); // 1.6384 MB

    if (ws_size >= tab_bytes && batch > 0) {
        float* tab = (float*)d_ws;

        softmax_rows_kernel<<<N_LEAVES, 64, 0, stream>>>(lp, tab);

        const int nchunks = (batch + CHUNK - 1) / CHUNK;
        const int nblk = nchunks < NBLK ? nchunks : NBLK;
        tree_stream_kernel<<<nblk, TPB, 0, stream>>>(
            x, sf, st, (const f32x4*)tab, (f32x4*)out, batch, nchunks);
    } else {
        fused_kernel<<<(batch + 255) / 256, 256, 0, stream>>>(
            x, sf, st, lp, out, batch);
    }
}